// Round 3
// baseline (172.962 us; speedup 1.0000x reference)
//
#include <hip/hip_runtime.h>
#include <stdint.h>

#define BB 8
#define SS 8192
#define DD 512

#define TOK_CS 256
#define TOK_CE 257
#define TOK_MEM 258
#define TOK_TS 259
#define TOK_TE 260

#define SEGS 256           // segments per row
#define PB 32              // positions per segment (SS / SEGS)

typedef float vfloat4 __attribute__((ext_vector_type(4)));
typedef unsigned long long u64;

// ---------------------------------------------------------------------------
// Kernel 1 (meta): unchanged (verified). grid = B*SEGS = 2048 blocks x 256.
// meta bits: 0..47 one-hot mask | 48 TS | 49 TE | 50 MEM_EXEC | 52.. token
// ---------------------------------------------------------------------------
__global__ __launch_bounds__(256) void meta_kernel(const int* __restrict__ tokens,
                                                   u64* __restrict__ meta) {
    __shared__ int tloc[PB + 8];              // local tokens with 8-token front halo
    __shared__ int rcs[4];
    __shared__ int rce[4];

    const int blk = blockIdx.x;
    const int row = blk >> 8;                 // / SEGS
    const int seg = blk & (SEGS - 1);
    const int start = seg * PB;
    const int tid = threadIdx.x;
    const int lane = tid & 63;
    const int wv = tid >> 6;
    const int* rt = tokens + (size_t)row * SS;

    // ---- phase A: prefix carry over [0, start) ----
    int maxcs = -1, anyce = 0;
    for (int j = tid; j < start; j += 256) {   // strided; later j larger -> last hit = max
        int v = rt[j];
        if (v == TOK_CS) maxcs = j;
        if (v == TOK_CE) anyce = 1;
    }
    #pragma unroll
    for (int off = 32; off > 0; off >>= 1) {
        int a = __shfl_down(maxcs, off);
        int b = __shfl_down(anyce, off);
        if (a > maxcs) maxcs = a;
        anyce |= b;
    }
    if (lane == 0) { rcs[wv] = maxcs; rce[wv] = anyce; }

    // local tokens + halo
    if (tid < PB + 8) {
        int g = start - 8 + tid;
        tloc[tid] = (g >= 0) ? rt[g] : 0;     // 0 is never MEM
    }
    __syncthreads();
    int carry_cs = rcs[0], carry_ce = rce[0];
    #pragma unroll
    for (int w = 1; w < 4; ++w) {
        if (rcs[w] > carry_cs) carry_cs = rcs[w];
        carry_ce |= rce[w];
    }

    // ---- phase B: 32-lane inclusive (max,or) scan over PB positions ----
    if (tid < PB) {
        const int myv = tloc[8 + tid];
        int cs_scan = (myv == TOK_CS) ? (start + tid) : -1;
        int ce_scan = (myv == TOK_CE) ? 1 : 0;

        #pragma unroll
        for (int off = 1; off < PB; off <<= 1) {
            int u = __shfl_up(cs_scan, off);
            int w = __shfl_up(ce_scan, off);
            if (tid >= off) {
                if (u > cs_scan) cs_scan = u;
                ce_scan |= w;
            }
        }
        if (carry_cs > cs_scan) cs_scan = carry_cs;
        ce_scan |= carry_ce;

        const int i = start + tid;
        const int v = myv;
        u64 m = ((u64)v) << 52;

        // code-region address one-hot
        if (cs_scan >= 0 && ce_scan == 0 && v < 256) {
            int sp = i - cs_scan - 1;
            if (sp >= 0) {
                int bo = sp & 7;
                if (bo < 5) {
                    int addr = ((sp >> 3) << 3) + 2 + bo;   // PC_OFFSET=2
                    addr &= 4095;
                    m |= (1ull << (addr & 15))
                       | (1ull << (16 + ((addr >> 4) & 15)))
                       | (1ull << (32 + ((addr >> 8) & 15)));
                }
            }
        }

        // MEM-op scatter, gathered from up to 8 positions back
        #pragma unroll
        for (int off = 0; off < 4; ++off) {
            int jj = i - 5 - off;
            int lj = jj - start + 8;            // >= 0 since jj >= i-8 >= start-8
            if (jj >= 0 && (jj + 8) < SS && tloc[lj] == TOK_MEM) {
                int a = ((tloc[lj + 1] | (tloc[lj + 2] << 8)) & 4095) + off;
                a &= 4095;
                m |= (1ull << (a & 15))
                   | (1ull << (16 + ((a >> 4) & 15)))
                   | (1ull << (32 + ((a >> 8) & 15)));
            }
        }

        // flag dims
        if (v == TOK_TS) m |= (1ull << 48);
        if (v == TOK_TE) m |= (1ull << 49);
        if (v == TOK_MEM && (i + 8) < SS) m |= (1ull << 50);

        meta[(size_t)row * SS + start + tid] = m;
    }
}

// ---------------------------------------------------------------------------
// Kernel 2 (writer), phase-split "fill-like" version.
// Each wave owns 8 consecutive positions:
//   phase 1: 8 wave-uniform meta loads (readfirstlane base -> scalar-load
//            eligible, lands in SGPRs)
//   phase 2: all 16 embed row-half loads issued back-to-back (max MLP,
//            no stores interleaved)
//   phase 3: register patch
//   phase 4: 16 back-to-back 1KB stores — a pure store burst like the
//            6.5 TB/s fillBuffer reference.
// ---------------------------------------------------------------------------
__global__ __launch_bounds__(256) void write_kernel(const u64* __restrict__ meta,
                                                    const vfloat4* __restrict__ embed4,
                                                    vfloat4* __restrict__ out) {
    const int blk = blockIdx.x;
    const int tid = threadIdx.x;
    const int lane = tid & 63;
    const int wv = tid >> 6;                    // 0..3

    const size_t base = (size_t)blk * PB;       // block's first global position
    // wave-uniform local offset, forced into SGPR so meta loads scalarize
    const int p0 = __builtin_amdgcn_readfirstlane(wv * 8);
    const u64* mrow = meta + base + p0;

    // ---- phase 1: 8 uniform meta loads ----
    u64 mq[8];
    #pragma unroll
    for (int p = 0; p < 8; ++p) mq[p] = mrow[p];

    // ---- phase 2: all 16 embed loads upfront ----
    vfloat4 val[16];
    #pragma unroll
    for (int p = 0; p < 8; ++p) {
        const int tok = (int)(mq[p] >> 52);
        const vfloat4* e = embed4 + (size_t)tok * 128;
        val[2 * p]     = e[lane];
        val[2 * p + 1] = e[64 + lane];
    }

    // ---- phase 3: patch in registers ----
    #pragma unroll
    for (int p = 0; p < 8; ++p) {
        const u64 m = mq[p];
        // chunk 0 (dims lane*4 .. lane*4+3): one-hot region 206..253
        if (lane >= 51) {
            #pragma unroll
            for (int j = 0; j < 4; ++j) {
                int r = lane * 4 + j - 206;
                if (r >= 0 && r < 48 && ((m >> r) & 1ull)) val[2 * p][j] = 1.0f;
            }
        }
        // chunk 1 (dims 256+lane*4 ..): lane 50 covers dims 456..459
        if (lane == 50) {
            #pragma unroll
            for (int j = 0; j < 3; ++j)
                if ((m >> (48 + j)) & 1ull) val[2 * p + 1][j] = 1.0f;
        }
    }

    // ---- phase 4: pure store burst, 16 x 1KB contiguous ----
    vfloat4* orow = out + (base + p0) * 128;
    #pragma unroll
    for (int p = 0; p < 8; ++p) {
        orow[p * 128 + lane]      = val[2 * p];
        orow[p * 128 + 64 + lane] = val[2 * p + 1];
    }
}

extern "C" void kernel_launch(void* const* d_in, const int* in_sizes, int n_in,
                              void* d_out, int out_size, void* d_ws, size_t ws_size,
                              hipStream_t stream) {
    const float* embed = (const float*)d_in[0];   // [272, 512] fp32
    const int* tokens = (const int*)d_in[1];      // [8, 8192] int32

    u64* meta = (u64*)d_ws;                       // 8*8192*8B = 512 KB

    meta_kernel<<<BB * SEGS, 256, 0, stream>>>(tokens, meta);
    // DOUBLE LAUNCH (idempotent): second dispatch makes the writer's own
    // duration directly observable in dur_us for decomposition.
    write_kernel<<<BB * SEGS, 256, 0, stream>>>(
        meta, (const vfloat4*)embed, (vfloat4*)d_out);
    write_kernel<<<BB * SEGS, 256, 0, stream>>>(
        meta, (const vfloat4*)embed, (vfloat4*)d_out);
}

// Round 4
// 150.074 us; speedup vs baseline: 1.1525x; 1.1525x over previous
//
#include <hip/hip_runtime.h>
#include <stdint.h>

#define BB 8
#define SS 8192
#define DD 512

#define TOK_CS 256
#define TOK_CE 257
#define TOK_MEM 258
#define TOK_TS 259
#define TOK_TE 260

#define SEGS 256           // segments per row
#define PB 32              // positions per segment (SS / SEGS)

typedef float vfloat4 __attribute__((ext_vector_type(4)));
typedef unsigned long long u64;

// ---------------------------------------------------------------------------
// Single fused kernel (final form). Grid = B*SEGS = 2048 blocks x 256 threads.
//   phase A: redundant prefix scan of tokens[0..start) -> carry (maxCS, anyCE)
//   phase B: 32-lane shfl inclusive scan -> per-position meta word in LDS
//   phase C: phase-split writer (measured standalone at 23.5 us = 5.7 TB/s,
//            90% of the fillBuffer reference BW). Per wave (8 positions):
//            8 LDS meta broadcasts -> 16 back-to-back embed loads ->
//            register patch -> 16 back-to-back 1KB stores.
// meta bits: 0..47 one-hot mask | 48 TS | 49 TE | 50 MEM_EXEC | 52.. token
// ---------------------------------------------------------------------------
__global__ __launch_bounds__(256) void fused_kernel(const int* __restrict__ tokens,
                                                    const vfloat4* __restrict__ embed4,
                                                    vfloat4* __restrict__ out) {
    __shared__ int tloc[PB + 8];              // local tokens with 8-token front halo
    __shared__ u64 mlds[PB];                  // per-position meta
    __shared__ int rcs[4];
    __shared__ int rce[4];

    const int blk = blockIdx.x;
    const int row = blk >> 8;                 // / SEGS
    const int seg = blk & (SEGS - 1);
    const int start = seg * PB;
    const int tid = threadIdx.x;
    const int lane = tid & 63;
    const int wv = tid >> 6;
    const int* rt = tokens + (size_t)row * SS;

    // ---- phase A: prefix carry over [0, start) ----
    int maxcs = -1, anyce = 0;
    for (int j = tid; j < start; j += 256) {   // strided; later j larger -> last hit = max
        int v = rt[j];
        if (v == TOK_CS) maxcs = j;
        if (v == TOK_CE) anyce = 1;
    }
    #pragma unroll
    for (int off = 32; off > 0; off >>= 1) {
        int a = __shfl_down(maxcs, off);
        int b = __shfl_down(anyce, off);
        if (a > maxcs) maxcs = a;
        anyce |= b;
    }
    if (lane == 0) { rcs[wv] = maxcs; rce[wv] = anyce; }

    // local tokens + halo
    if (tid < PB + 8) {
        int g = start - 8 + tid;
        tloc[tid] = (g >= 0) ? rt[g] : 0;     // 0 is never MEM
    }
    __syncthreads();
    int carry_cs = rcs[0], carry_ce = rce[0];
    #pragma unroll
    for (int w = 1; w < 4; ++w) {
        if (rcs[w] > carry_cs) carry_cs = rcs[w];
        carry_ce |= rce[w];
    }

    // ---- phase B: 32-lane inclusive (max,or) scan over PB positions ----
    if (tid < PB) {
        const int myv = tloc[8 + tid];
        int cs_scan = (myv == TOK_CS) ? (start + tid) : -1;
        int ce_scan = (myv == TOK_CE) ? 1 : 0;

        #pragma unroll
        for (int off = 1; off < PB; off <<= 1) {
            int u = __shfl_up(cs_scan, off);
            int w = __shfl_up(ce_scan, off);
            if (tid >= off) {
                if (u > cs_scan) cs_scan = u;
                ce_scan |= w;
            }
        }
        if (carry_cs > cs_scan) cs_scan = carry_cs;
        ce_scan |= carry_ce;

        const int i = start + tid;
        const int v = myv;
        u64 m = ((u64)v) << 52;

        // code-region address one-hot
        if (cs_scan >= 0 && ce_scan == 0 && v < 256) {
            int sp = i - cs_scan - 1;
            if (sp >= 0) {
                int bo = sp & 7;
                if (bo < 5) {
                    int addr = ((sp >> 3) << 3) + 2 + bo;   // PC_OFFSET=2
                    addr &= 4095;
                    m |= (1ull << (addr & 15))
                       | (1ull << (16 + ((addr >> 4) & 15)))
                       | (1ull << (32 + ((addr >> 8) & 15)));
                }
            }
        }

        // MEM-op scatter, gathered from up to 8 positions back
        #pragma unroll
        for (int off = 0; off < 4; ++off) {
            int jj = i - 5 - off;
            int lj = jj - start + 8;            // >= 0 since jj >= i-8 >= start-8
            if (jj >= 0 && (jj + 8) < SS && tloc[lj] == TOK_MEM) {
                int a = ((tloc[lj + 1] | (tloc[lj + 2] << 8)) & 4095) + off;
                a &= 4095;
                m |= (1ull << (a & 15))
                   | (1ull << (16 + ((a >> 4) & 15)))
                   | (1ull << (32 + ((a >> 8) & 15)));
            }
        }

        // flag dims
        if (v == TOK_TS) m |= (1ull << 48);
        if (v == TOK_TE) m |= (1ull << 49);
        if (v == TOK_MEM && (i + 8) < SS) m |= (1ull << 50);

        mlds[tid] = m;
    }
    __syncthreads();

    // ---- phase C: phase-split writer; each wave owns 8 positions ----
    const int p0 = wv * 8;                      // wave-uniform

    // 1) meta broadcast reads from LDS
    u64 mq[8];
    #pragma unroll
    for (int p = 0; p < 8; ++p) mq[p] = mlds[p0 + p];

    // 2) all 16 embed row-half loads back-to-back (max MLP)
    vfloat4 val[16];
    #pragma unroll
    for (int p = 0; p < 8; ++p) {
        const int tok = (int)(mq[p] >> 52);
        const vfloat4* e = embed4 + (size_t)tok * 128;
        val[2 * p]     = e[lane];
        val[2 * p + 1] = e[64 + lane];
    }

    // 3) patch in registers
    #pragma unroll
    for (int p = 0; p < 8; ++p) {
        const u64 m = mq[p];
        // chunk 0 (dims lane*4 .. lane*4+3): one-hot region 206..253
        if (lane >= 51) {
            #pragma unroll
            for (int j = 0; j < 4; ++j) {
                int r = lane * 4 + j - 206;
                if (r >= 0 && r < 48 && ((m >> r) & 1ull)) val[2 * p][j] = 1.0f;
            }
        }
        // chunk 1 (dims 256+lane*4 ..): lane 50 covers dims 456..459
        if (lane == 50) {
            #pragma unroll
            for (int j = 0; j < 3; ++j)
                if ((m >> (48 + j)) & 1ull) val[2 * p + 1][j] = 1.0f;
        }
    }

    // 4) pure store burst: 16 x 1KB contiguous
    vfloat4* orow = out + ((size_t)blk * PB + p0) * 128;
    #pragma unroll
    for (int p = 0; p < 8; ++p) {
        orow[p * 128 + lane]      = val[2 * p];
        orow[p * 128 + 64 + lane] = val[2 * p + 1];
    }
}

extern "C" void kernel_launch(void* const* d_in, const int* in_sizes, int n_in,
                              void* d_out, int out_size, void* d_ws, size_t ws_size,
                              hipStream_t stream) {
    const float* embed = (const float*)d_in[0];   // [272, 512] fp32
    const int* tokens = (const int*)d_in[1];      // [8, 8192] int32

    fused_kernel<<<BB * SEGS, 256, 0, stream>>>(
        tokens, (const vfloat4*)embed, (vfloat4*)d_out);
}